// Round 1
// baseline (700.953 us; speedup 1.0000x reference)
//
#include <hip/hip_runtime.h>
#include <stdint.h>

// lap = I - adj/k where adj is the k-NN graph (including self) of x under
// euclidean distance, ties broken toward lower index (matches jax.lax.top_k).
// Shapes fixed by setup_inputs(): B=4, N=4096, C=3, k=20 (k read from device).

constexpr int Npts = 4096;
constexpr int BLK  = 256;
constexpr int MAXK = 32;

__device__ inline unsigned long long u64min(unsigned long long a, unsigned long long b) {
    return a < b ? a : b;
}

__device__ inline unsigned long long wave_min64(unsigned long long v) {
#pragma unroll
    for (int off = 1; off < 64; off <<= 1) {
        unsigned long long o = __shfl_xor(v, off, 64);
        v = u64min(v, o);
    }
    return v;
}

__global__ __launch_bounds__(BLK) void gcn_lap_kernel(const float* __restrict__ x,
                                                      const int* __restrict__ kptr,
                                                      float* __restrict__ out) {
    __shared__ float pts[Npts * 3];                 // 48 KB: this batch's points
    __shared__ float rowbuf[Npts];                  // 16 KB: output row staging
    __shared__ unsigned long long wkeys[4 * MAXK];  // per-wave top-k keys

    const int row  = blockIdx.x;       // b*N + i
    const int b    = row >> 12;        // / 4096
    const int i    = row & (Npts - 1);
    const int tid  = threadIdx.x;
    const int lane = tid & 63;
    const int wv   = tid >> 6;

    int k = *kptr;
    if (k > MAXK) k = MAXK;
    if (k < 1) k = 1;

    // ---- stage points (float4 coalesced) and zero row buffer ----
    const float4* xsrc = (const float4*)(x + (size_t)b * (Npts * 3));
    float4* pdst = (float4*)pts;
#pragma unroll
    for (int c = 0; c < (Npts * 3 / 4) / BLK; ++c)
        pdst[tid + BLK * c] = xsrc[tid + BLK * c];
    float4* rb4 = (float4*)rowbuf;
#pragma unroll
    for (int c = 0; c < (Npts / 4) / BLK; ++c)
        rb4[tid + BLK * c] = make_float4(0.f, 0.f, 0.f, 0.f);
    __syncthreads();

    // ---- distances from point i to this wave's 1024 candidates ----
    const float ax = pts[3 * i], ay = pts[3 * i + 1], az = pts[3 * i + 2];
    const float sqi = __fadd_rn(__fadd_rn(__fmul_rn(ax, ax), __fmul_rn(ay, ay)),
                                __fmul_rn(az, az));

    const int jbase = (wv << 10) | lane;  // wave owns [wv*1024, wv*1024+1024)
    float d2[16];
#pragma unroll
    for (int c = 0; c < 16; ++c) {
        const int j = jbase + (c << 6);
        const float bx = pts[3 * j], by = pts[3 * j + 1], bz = pts[3 * j + 2];
        const float sqj = __fadd_rn(__fadd_rn(__fmul_rn(bx, bx), __fmul_rn(by, by)),
                                    __fmul_rn(bz, bz));
        const float dot = __fadd_rn(__fadd_rn(__fmul_rn(ax, bx), __fmul_rn(ay, by)),
                                    __fmul_rn(az, bz));
        const float v = __fsub_rn(__fadd_rn(sqi, sqj), __fmul_rn(2.0f, dot));
        d2[c] = fmaxf(v, 0.0f);  // clamp like reference; bits monotone for >=0
    }

    // key = (dist_bits << 32) | j  -> u64 min == (smallest dist, then lowest j)
    unsigned used = 0;
    auto localmin = [&]() {
        unsigned long long best = ~0ull;
#pragma unroll
        for (int c = 0; c < 16; ++c) {
            const unsigned long long key =
                ((unsigned long long)__float_as_uint(d2[c]) << 32) |
                (unsigned)(jbase + (c << 6));
            if (!(used & (1u << c))) best = u64min(best, key);
        }
        return best;
    };

    // ---- phase 1: each wave extracts its own top-k (barrier-free) ----
    unsigned long long cur = localmin();
    for (int t = 0; t < k; ++t) {
        const unsigned long long m = wave_min64(cur);
        if (lane == 0) wkeys[wv * k + t] = m;
        if (cur == m) {               // unique keys -> exactly one winner lane
            const int c = (((int)(unsigned)(m & 0xffffffffu)) - jbase) >> 6;
            used |= (1u << c);
            cur = localmin();
        }
    }
    __syncthreads();

    // ---- phase 2: wave 0 merges 4*k candidates, scatters -1/k' into rowbuf ----
    if (wv == 0) {
        const int nk = 4 * k;  // <= 128
        unsigned long long k0 = (lane < nk) ? wkeys[lane] : ~0ull;
        unsigned long long k1 = (lane + 64 < nk) ? wkeys[lane + 64] : ~0ull;
        const float r = 1.0f / sqrtf((float)k);
        const float negrr = -__fmul_rn(r, r);   // = -(dinv_i*dinv_j), deg==k rows
        unsigned u2 = 0;
        for (int t = 0; t < k; ++t) {
            const unsigned long long c0 = (u2 & 1u) ? ~0ull : k0;
            const unsigned long long c1 = (u2 & 2u) ? ~0ull : k1;
            const unsigned long long m = wave_min64(u64min(c0, c1));
            if (c0 == m) {
                u2 |= 1u;
                rowbuf[(int)(unsigned)(m & 0xffffffffu)] = negrr;
            } else if (c1 == m) {
                u2 |= 2u;
                rowbuf[(int)(unsigned)(m & 0xffffffffu)] = negrr;
            }
        }
    }
    __syncthreads();

    // ---- phase 3: stream the row out, adding the identity diagonal ----
    float4* o4 = (float4*)(out + (size_t)row * Npts);
#pragma unroll
    for (int c = 0; c < (Npts / 4) / BLK; ++c) {
        const int q = tid + BLK * c;
        float4 v = rb4[q];
        const int j0 = q << 2;
        v.x = __fadd_rn(v.x, (j0 + 0 == i) ? 1.0f : 0.0f);
        v.y = __fadd_rn(v.y, (j0 + 1 == i) ? 1.0f : 0.0f);
        v.z = __fadd_rn(v.z, (j0 + 2 == i) ? 1.0f : 0.0f);
        v.w = __fadd_rn(v.w, (j0 + 3 == i) ? 1.0f : 0.0f);
        o4[q] = v;
    }
}

extern "C" void kernel_launch(void* const* d_in, const int* in_sizes, int n_in,
                              void* d_out, int out_size, void* d_ws, size_t ws_size,
                              hipStream_t stream) {
    const float* x    = (const float*)d_in[0];
    const int*   kptr = (const int*)d_in[1];
    float*       out  = (float*)d_out;
    const int B = in_sizes[0] / (Npts * 3);
    hipLaunchKernelGGL(gcn_lap_kernel, dim3(B * Npts), dim3(BLK), 0, stream,
                       x, kptr, out);
}

// Round 2
// 698.398 us; speedup vs baseline: 1.0037x; 1.0037x over previous
//
#include <hip/hip_runtime.h>
#include <stdint.h>

// lap = I - adj/k where adj is the k-NN graph (including self) of x under
// euclidean distance, ties broken toward lower index (matches jax.lax.top_k).
// Shapes fixed by setup_inputs(): B=4, N=4096, C=3, k=20 (k read from device).

constexpr int Npts = 4096;
constexpr int BLK  = 256;
constexpr int MAXK = 32;

__device__ inline unsigned long long u64min(unsigned long long a, unsigned long long b) {
    return a < b ? a : b;
}

__device__ inline unsigned long long wave_min64(unsigned long long v) {
#pragma unroll
    for (int off = 1; off < 64; off <<= 1) {
        unsigned long long o = __shfl_xor(v, off, 64);
        v = u64min(v, o);
    }
    return v;
}

__global__ __launch_bounds__(BLK) void gcn_lap_kernel(const float* __restrict__ x,
                                                      const int* __restrict__ kptr,
                                                      float* __restrict__ out) {
    __shared__ float pts[Npts * 3];                 // 48 KB: this batch's points
    __shared__ float rowbuf[Npts];                  // 16 KB: output row staging
    __shared__ unsigned long long wkeys[4 * MAXK];  // per-wave top-k keys

    const int row  = blockIdx.x;       // b*N + i
    const int b    = row >> 12;        // / 4096
    const int i    = row & (Npts - 1);
    const int tid  = threadIdx.x;
    const int lane = tid & 63;
    const int wv   = tid >> 6;

    int k = *kptr;
    if (k > MAXK) k = MAXK;
    if (k < 1) k = 1;

    // ---- stage points (float4 coalesced) and zero row buffer ----
    const float4* xsrc = (const float4*)(x + (size_t)b * (Npts * 3));
    float4* pdst = (float4*)pts;
#pragma unroll
    for (int c = 0; c < (Npts * 3 / 4) / BLK; ++c)
        pdst[tid + BLK * c] = xsrc[tid + BLK * c];
    float4* rb4 = (float4*)rowbuf;
#pragma unroll
    for (int c = 0; c < (Npts / 4) / BLK; ++c)
        rb4[tid + BLK * c] = make_float4(0.f, 0.f, 0.f, 0.f);
    __syncthreads();

    // ---- distances from point i to this wave's 1024 candidates ----
    const float ax = pts[3 * i], ay = pts[3 * i + 1], az = pts[3 * i + 2];
    const float sqi = __fadd_rn(__fadd_rn(__fmul_rn(ax, ax), __fmul_rn(ay, ay)),
                                __fmul_rn(az, az));

    const int jbase = (wv << 10) | lane;  // wave owns [wv*1024, wv*1024+1024)
    float d2[16];
#pragma unroll
    for (int c = 0; c < 16; ++c) {
        const int j = jbase + (c << 6);
        const float bx = pts[3 * j], by = pts[3 * j + 1], bz = pts[3 * j + 2];
        const float sqj = __fadd_rn(__fadd_rn(__fmul_rn(bx, bx), __fmul_rn(by, by)),
                                    __fmul_rn(bz, bz));
        const float dot = __fadd_rn(__fadd_rn(__fmul_rn(ax, bx), __fmul_rn(ay, by)),
                                    __fmul_rn(az, bz));
        const float v = __fsub_rn(__fadd_rn(sqi, sqj), __fmul_rn(2.0f, dot));
        d2[c] = fmaxf(v, 0.0f);  // clamp like reference; bits monotone for >=0
    }

    // key = (dist_bits << 32) | j  -> u64 min == (smallest dist, then lowest j)
    unsigned used = 0;
    auto localmin = [&]() {
        unsigned long long best = ~0ull;
#pragma unroll
        for (int c = 0; c < 16; ++c) {
            const unsigned long long key =
                ((unsigned long long)__float_as_uint(d2[c]) << 32) |
                (unsigned)(jbase + (c << 6));
            if (!(used & (1u << c))) best = u64min(best, key);
        }
        return best;
    };

    // ---- phase 1: each wave extracts its own top-k (barrier-free) ----
    unsigned long long cur = localmin();
    for (int t = 0; t < k; ++t) {
        const unsigned long long m = wave_min64(cur);
        if (lane == 0) wkeys[wv * k + t] = m;
        if (cur == m) {               // unique keys -> exactly one winner lane
            const int c = (((int)(unsigned)(m & 0xffffffffu)) - jbase) >> 6;
            used |= (1u << c);
            cur = localmin();
        }
    }
    __syncthreads();

    // ---- phase 2: wave 0 merges 4*k candidates, scatters -1/k' into rowbuf ----
    if (wv == 0) {
        const int nk = 4 * k;  // <= 128
        unsigned long long k0 = (lane < nk) ? wkeys[lane] : ~0ull;
        unsigned long long k1 = (lane + 64 < nk) ? wkeys[lane + 64] : ~0ull;
        const float r = 1.0f / sqrtf((float)k);
        const float negrr = -__fmul_rn(r, r);   // = -(dinv_i*dinv_j), deg==k rows
        unsigned u2 = 0;
        for (int t = 0; t < k; ++t) {
            const unsigned long long c0 = (u2 & 1u) ? ~0ull : k0;
            const unsigned long long c1 = (u2 & 2u) ? ~0ull : k1;
            const unsigned long long m = wave_min64(u64min(c0, c1));
            if (c0 == m) {
                u2 |= 1u;
                rowbuf[(int)(unsigned)(m & 0xffffffffu)] = negrr;
            } else if (c1 == m) {
                u2 |= 2u;
                rowbuf[(int)(unsigned)(m & 0xffffffffu)] = negrr;
            }
        }
    }
    __syncthreads();

    // ---- phase 3: stream the row out, adding the identity diagonal ----
    float4* o4 = (float4*)(out + (size_t)row * Npts);
#pragma unroll
    for (int c = 0; c < (Npts / 4) / BLK; ++c) {
        const int q = tid + BLK * c;
        float4 v = rb4[q];
        const int j0 = q << 2;
        v.x = __fadd_rn(v.x, (j0 + 0 == i) ? 1.0f : 0.0f);
        v.y = __fadd_rn(v.y, (j0 + 1 == i) ? 1.0f : 0.0f);
        v.z = __fadd_rn(v.z, (j0 + 2 == i) ? 1.0f : 0.0f);
        v.w = __fadd_rn(v.w, (j0 + 3 == i) ? 1.0f : 0.0f);
        o4[q] = v;
    }
}

extern "C" void kernel_launch(void* const* d_in, const int* in_sizes, int n_in,
                              void* d_out, int out_size, void* d_ws, size_t ws_size,
                              hipStream_t stream) {
    const float* x    = (const float*)d_in[0];
    const int*   kptr = (const int*)d_in[1];
    float*       out  = (float*)d_out;
    const int B = in_sizes[0] / (Npts * 3);
    hipLaunchKernelGGL(gcn_lap_kernel, dim3(B * Npts), dim3(BLK), 0, stream,
                       x, kptr, out);
}

// Round 3
// 379.536 us; speedup vs baseline: 1.8469x; 1.8401x over previous
//
#include <hip/hip_runtime.h>
#include <stdint.h>

// lap = I - adj/k, adj = exact k-NN graph (incl. self) under euclidean
// distance with jax.lax.top_k tie-break (lower index wins).
// Key = (f32_bits(d2) << 32) | j : u64 min == (smallest d2, then lowest j).
// One wave per output row; winner-only group rescan; register row-mask output.

constexpr int Npts = 4096;
constexpr int BLK  = 512;   // 8 waves = 8 rows per block

typedef unsigned long long u64;

__device__ inline u64 u64min(u64 a, u64 b) { return a < b ? a : b; }

__device__ inline u64 wave_min64(u64 v) {
#pragma unroll
    for (int off = 1; off < 64; off <<= 1) {
        u64 o = __shfl_xor(v, off, 64);
        v = u64min(v, o);
    }
    return v;
}

__global__ __launch_bounds__(BLK, 4) void gcn_lap_kernel(const float* __restrict__ x,
                                                         const int* __restrict__ kptr,
                                                         float* __restrict__ out) {
    __shared__ float4 pts4[Npts];   // 64 KB: (x, y, z, |p|^2) per point

    const int tid  = threadIdx.x;
    const int lane = tid & 63;
    const int wv   = tid >> 6;
    const int b    = blockIdx.x >> 9;                  // 512 blocks per batch
    const int i    = ((blockIdx.x & 511) << 3) | wv;   // this wave's row (0..4095)

    int k = *kptr;
    if (k < 1) k = 1;
    if (k > Npts) k = Npts;

    // ---- stage points once per block: (x,y,z,sq), sq with reference rounding ----
    const float* xb = x + (size_t)b * (Npts * 3);
#pragma unroll
    for (int s = 0; s < Npts / BLK; ++s) {
        const int p = tid + BLK * s;
        const float bx = xb[3 * p], by = xb[3 * p + 1], bz = xb[3 * p + 2];
        const float sq = __fadd_rn(__fadd_rn(__fmul_rn(bx, bx), __fmul_rn(by, by)),
                                   __fmul_rn(bz, bz));
        pts4[p] = make_float4(bx, by, bz, sq);
    }
    __syncthreads();

    const float4 pi = pts4[i];                 // broadcast read (free)
    const float ax = pi.x, ay = pi.y, az = pi.z, sqi = pi.w;

    // ---- upfront: 64 candidate d2 in regs + 8 group-min keys ----
    float d2[64];
    u64 gkey[8];
#pragma unroll
    for (int G = 0; G < 8; ++G) gkey[G] = ~0ull;
#pragma unroll
    for (int c = 0; c < 64; ++c) {
        const int j = (c << 6) | lane;         // coalesced, 2-way bank alias
        const float4 pj = pts4[j];
        const float dot = __fadd_rn(__fadd_rn(__fmul_rn(ax, pj.x), __fmul_rn(ay, pj.y)),
                                    __fmul_rn(az, pj.z));
        const float v = __fsub_rn(__fadd_rn(sqi, pj.w), __fmul_rn(2.0f, dot));
        const float dd = fmaxf(v, 0.0f);
        d2[c] = dd;
        const u64 key = ((u64)__float_as_uint(dd) << 32) | (unsigned)j;
        gkey[c >> 3] = u64min(gkey[c >> 3], key);
    }
    u64 lkey = gkey[0];
#pragma unroll
    for (int G = 1; G < 8; ++G) lkey = u64min(lkey, gkey[G]);

    u64 used = 0;    // per-lane candidate-consumed bits (by c)
    u64 wmask = 0;   // per-lane output-ownership bits (by q*4+e)

    // ---- k extractions: wave-min + winner-only group rescan ----
    for (int t = 0; t < k; ++t) {
        const u64 m = wave_min64(lkey);
        const unsigned j = (unsigned)(m & 0xffffffffu);   // winner index, uniform
        if (((j >> 2) & 63u) == (unsigned)lane)           // write-owner lane
            wmask |= 1ull << (((j >> 8) << 2) | (j & 3u));
        if (lkey == m) {                                  // unique keys -> one winner
            const unsigned c = j >> 6;                    // j = c*64 + lane
            used |= 1ull << c;
            const unsigned Gw = c >> 3;
#pragma unroll
            for (unsigned G = 0; G < 8; ++G) {
                if (Gw == G) {                            // static-index rescan
                    float bd2 = __uint_as_float(0x7f800000u);   // +inf
                    unsigned bc = G * 8;
#pragma unroll
                    for (unsigned e = 0; e < 8; ++e) {
                        const unsigned cc = G * 8 + e;
                        const float vv = (used & (1ull << cc))
                                             ? __uint_as_float(0x7f800000u)
                                             : d2[cc];
                        if (vv < bd2) { bd2 = vv; bc = cc; }  // strict < : lowest c on tie
                    }
                    gkey[G] = ((u64)__float_as_uint(bd2) << 32) |
                              (unsigned)((bc << 6) | (unsigned)lane);
                }
            }
            lkey = gkey[0];
#pragma unroll
            for (int G = 1; G < 8; ++G) lkey = u64min(lkey, gkey[G]);
        }
    }

    // ---- emit row from register mask: coalesced float4 stream ----
    const float r = 1.0f / sqrtf((float)k);
    const float negrr = -__fmul_rn(r, r);      // -(dinv_i*dinv_j), deg == k exactly
    float4* o4 = (float4*)(out + (size_t)(b * Npts + i) * Npts);
#pragma unroll
    for (int q = 0; q < 16; ++q) {
        const int j0 = (q << 8) | (lane << 2); // element index of v.x
        float4 v;
        v.x = ((wmask >> (q * 4 + 0)) & 1ull) ? negrr : 0.0f;
        v.y = ((wmask >> (q * 4 + 1)) & 1ull) ? negrr : 0.0f;
        v.z = ((wmask >> (q * 4 + 2)) & 1ull) ? negrr : 0.0f;
        v.w = ((wmask >> (q * 4 + 3)) & 1ull) ? negrr : 0.0f;
        v.x = __fadd_rn(v.x, (j0 + 0 == i) ? 1.0f : 0.0f);
        v.y = __fadd_rn(v.y, (j0 + 1 == i) ? 1.0f : 0.0f);
        v.z = __fadd_rn(v.z, (j0 + 2 == i) ? 1.0f : 0.0f);
        v.w = __fadd_rn(v.w, (j0 + 3 == i) ? 1.0f : 0.0f);
        o4[(q << 6) | lane] = v;
    }
}

extern "C" void kernel_launch(void* const* d_in, const int* in_sizes, int n_in,
                              void* d_out, int out_size, void* d_ws, size_t ws_size,
                              hipStream_t stream) {
    const float* x    = (const float*)d_in[0];
    const int*   kptr = (const int*)d_in[1];
    float*       out  = (float*)d_out;
    const int B = in_sizes[0] / (Npts * 3);
    hipLaunchKernelGGL(gcn_lap_kernel, dim3(B * 512), dim3(BLK), 0, stream,
                       x, kptr, out);
}

// Round 4
// 150.041 us; speedup vs baseline: 4.6718x; 2.5296x over previous
//
#include <hip/hip_runtime.h>
#include <stdint.h>

// lap = I - adj/k, adj = exact k-NN graph (incl. self) under euclidean
// distance with jax.lax.top_k tie-break (lower index wins).
// Key = (f32_bits(d2) << 32) | j : u64 min == (smallest d2, then lowest j).
// One wave per row. NO per-lane distance array (R2 spilled 900MB of scratch):
// rescans recompute d2 from LDS with runtime-indexed addresses.

constexpr int Npts = 4096;
constexpr int BLK  = 512;   // 8 waves = 8 rows per block

typedef unsigned long long u64;

__device__ inline u64 u64min(u64 a, u64 b) { return a < b ? a : b; }

__device__ inline u64 wave_min64(u64 v) {
#pragma unroll
    for (int off = 1; off < 64; off <<= 1) {
        u64 o = __shfl_xor(v, off, 64);
        v = u64min(v, o);
    }
    return v;
}

// d2(i, j) with reference rounding (no fma contraction); deterministic, so
// recomputation is bitwise-identical to the upfront pass.
__device__ inline float cand_d2(const float4* __restrict__ pts4, unsigned j,
                                float ax, float ay, float az, float sqi) {
    const float4 pj = pts4[j];
    const float dot = __fadd_rn(__fadd_rn(__fmul_rn(ax, pj.x), __fmul_rn(ay, pj.y)),
                                __fmul_rn(az, pj.z));
    const float v = __fsub_rn(__fadd_rn(sqi, pj.w), __fmul_rn(2.0f, dot));
    return fmaxf(v, 0.0f);
}

__global__ __launch_bounds__(BLK, 4) void gcn_lap_kernel(const float* __restrict__ x,
                                                         const int* __restrict__ kptr,
                                                         float* __restrict__ out) {
    __shared__ float4 pts4[Npts];   // 64 KB: (x, y, z, |p|^2) per point

    const int tid  = threadIdx.x;
    const int lane = tid & 63;
    const int wv   = tid >> 6;
    const int b    = blockIdx.x >> 9;                  // 512 blocks per batch
    const int i    = ((blockIdx.x & 511) << 3) | wv;   // this wave's row (0..4095)

    int k = *kptr;
    if (k < 1) k = 1;
    if (k > Npts) k = Npts;

    // ---- stage points once per block: (x,y,z,sq), sq with reference rounding ----
    const float* xb = x + (size_t)b * (Npts * 3);
#pragma unroll
    for (int s = 0; s < Npts / BLK; ++s) {
        const int p = tid + BLK * s;
        const float bx = xb[3 * p], by = xb[3 * p + 1], bz = xb[3 * p + 2];
        const float sq = __fadd_rn(__fadd_rn(__fmul_rn(bx, bx), __fmul_rn(by, by)),
                                   __fmul_rn(bz, bz));
        pts4[p] = make_float4(bx, by, bz, sq);
    }
    __syncthreads();

    const float4 pi = pts4[i];                 // wave-uniform broadcast read
    const float ax = pi.x, ay = pi.y, az = pi.z, sqi = pi.w;

    // ---- upfront: per-lane min key of each 8-candidate group (no d2 array) ----
    u64 gkey[8];                               // static-index only -> registers
#pragma unroll
    for (int G = 0; G < 8; ++G) {
        u64 g = ~0ull;
#pragma unroll
        for (int e = 0; e < 8; ++e) {
            const unsigned c = G * 8 + e;
            const unsigned j = (c << 6) | (unsigned)lane;   // coalesced LDS read
            const float dd = cand_d2(pts4, j, ax, ay, az, sqi);
            g = u64min(g, ((u64)__float_as_uint(dd) << 32) | j);
        }
        gkey[G] = g;
    }
    u64 lkey = gkey[0];
#pragma unroll
    for (int G = 1; G < 8; ++G) lkey = u64min(lkey, gkey[G]);

    u64 used  = 0;   // per-lane consumed-candidate bits (by c = j>>6)
    u64 wmask = 0;   // per-lane output-ownership bits (by (q<<2)|elem)

    // ---- k extractions: wave-min + winner-only group recompute ----
    for (int t = 0; t < k; ++t) {
        const u64 m = wave_min64(lkey);
        if (m == ~0ull) break;                            // all candidates consumed
        const unsigned j = (unsigned)(m & 0xffffffffu);   // winner index, wave-uniform
        if (((j >> 2) & 63u) == (unsigned)lane)           // float4-owner lane marks it
            wmask |= 1ull << (((j >> 8) << 2) | (j & 3u));
        if (lkey == m) {                                  // unique keys -> one winner
            const unsigned cwin = j >> 6;
            used |= 1ull << cwin;
            const unsigned Gw = cwin >> 3;                // runtime group id
            u64 g = ~0ull;
#pragma unroll
            for (unsigned e = 0; e < 8; ++e) {            // runtime LDS addressing:
                const unsigned cc = (Gw << 3) + e;        // no register-array index
                const unsigned jj = (cc << 6) | (unsigned)lane;
                const float dd = cand_d2(pts4, jj, ax, ay, az, sqi);
                u64 key = ((u64)__float_as_uint(dd) << 32) | jj;
                if ((used >> cc) & 1ull) key = ~0ull;
                g = u64min(g, key);
            }
#pragma unroll
            for (unsigned G = 0; G < 8; ++G)              // predicated 2-reg writes
                if (Gw == G) gkey[G] = g;
            lkey = gkey[0];
#pragma unroll
            for (int G = 1; G < 8; ++G) lkey = u64min(lkey, gkey[G]);
        }
    }

    // ---- emit row from register mask: coalesced float4 stream ----
    const float r = 1.0f / sqrtf((float)k);
    const float negrr = -__fmul_rn(r, r);      // -(dinv_i*dinv_j); deg == k exactly
    float4* o4 = (float4*)(out + (size_t)(b * Npts + i) * Npts);
#pragma unroll
    for (int q = 0; q < 16; ++q) {
        const int j0 = (q << 8) | (lane << 2); // element index of v.x
        float4 v;
        v.x = ((wmask >> (q * 4 + 0)) & 1ull) ? negrr : 0.0f;
        v.y = ((wmask >> (q * 4 + 1)) & 1ull) ? negrr : 0.0f;
        v.z = ((wmask >> (q * 4 + 2)) & 1ull) ? negrr : 0.0f;
        v.w = ((wmask >> (q * 4 + 3)) & 1ull) ? negrr : 0.0f;
        v.x = __fadd_rn(v.x, (j0 + 0 == i) ? 1.0f : 0.0f);
        v.y = __fadd_rn(v.y, (j0 + 1 == i) ? 1.0f : 0.0f);
        v.z = __fadd_rn(v.z, (j0 + 2 == i) ? 1.0f : 0.0f);
        v.w = __fadd_rn(v.w, (j0 + 3 == i) ? 1.0f : 0.0f);
        o4[(q << 6) | lane] = v;
    }
}

extern "C" void kernel_launch(void* const* d_in, const int* in_sizes, int n_in,
                              void* d_out, int out_size, void* d_ws, size_t ws_size,
                              hipStream_t stream) {
    const float* x    = (const float*)d_in[0];
    const int*   kptr = (const int*)d_in[1];
    float*       out  = (float*)d_out;
    const int B = in_sizes[0] / (Npts * 3);
    hipLaunchKernelGGL(gcn_lap_kernel, dim3(B * 512), dim3(BLK), 0, stream,
                       x, kptr, out);
}

// Round 5
// 121.640 us; speedup vs baseline: 5.7625x; 1.2335x over previous
//
#include <hip/hip_runtime.h>
#include <stdint.h>

// lap = I - adj/k, adj = exact k-NN graph (incl. self) under euclidean
// distance with jax.lax.top_k tie-break (lower index wins).
// One wave per row. Per-lane sorted top-3 cache (fmin/med3 maintained) kills
// the R3 winner-rescan (60% of VALU issue). Exact: cache refill rescans all
// unconsumed candidates (rare: P(lane wins >=4 of 20) ~ 3e-4).

constexpr int Npts = 4096;
constexpr int BLK  = 512;   // 8 waves = 8 rows per block

typedef unsigned long long u64;

__device__ inline u64 u64min(u64 a, u64 b) { return a < b ? a : b; }

__device__ inline u64 wave_min64(u64 v) {
#pragma unroll
    for (int off = 1; off < 64; off <<= 1) {
        u64 o = __shfl_xor(v, off, 64);
        v = u64min(v, o);
    }
    return v;
}

// d2(i, j) with reference rounding (no fma contraction); deterministic ->
// recomputation (refill path) is bitwise-identical to the upfront pass.
__device__ inline float cand_d2(const float4* __restrict__ pts4, unsigned j,
                                float ax, float ay, float az, float sqi) {
    const float4 pj = pts4[j];
    const float dot = __fadd_rn(__fadd_rn(__fmul_rn(ax, pj.x), __fmul_rn(ay, pj.y)),
                                __fmul_rn(az, pj.z));
    const float v = __fsub_rn(__fadd_rn(sqi, pj.w), __fmul_rn(2.0f, dot));
    return fmaxf(v, 0.0f);   // a-b==0 gives +0.0 in RN, so sign bit never set
}

__global__ __launch_bounds__(BLK, 4) void gcn_lap_kernel(const float* __restrict__ x,
                                                         const int* __restrict__ kptr,
                                                         float* __restrict__ out) {
    __shared__ float4 pts4[Npts];   // 64 KB: (x, y, z, |p|^2) per point

    const int tid  = threadIdx.x;
    const int lane = tid & 63;
    const int wv   = tid >> 6;
    const int b    = blockIdx.x >> 9;                  // 512 blocks per batch
    const int i    = ((blockIdx.x & 511) << 3) | wv;   // this wave's row (0..4095)

    int k = *kptr;
    if (k < 1) k = 1;
    if (k > Npts) k = Npts;

    // ---- stage points once per block: (x,y,z,sq), sq with reference rounding ----
    const float* xb = x + (size_t)b * (Npts * 3);
#pragma unroll
    for (int s = 0; s < Npts / BLK; ++s) {
        const int p = tid + BLK * s;
        const float bx = xb[3 * p], by = xb[3 * p + 1], bz = xb[3 * p + 2];
        const float sq = __fadd_rn(__fadd_rn(__fmul_rn(bx, bx), __fmul_rn(by, by)),
                                   __fmul_rn(bz, bz));
        pts4[p] = make_float4(bx, by, bz, sq);
    }
    __syncthreads();

    const float4 pi = pts4[i];                 // wave-uniform broadcast read
    const float ax = pi.x, ay = pi.y, az = pi.z, sqi = pi.w;

    const float INF_F = __uint_as_float(0x7f800000u);

    // ---- upfront: per-lane sorted top-3 (d1<=d2<=d3) with indices; strict '<'
    //      keeps earlier (lower c -> lower j) on ties = top_k tie-break ----
    float da = INF_F, db = INF_F, dc = INF_F;
    unsigned ca = 0, cb = 0, cc = 0;
#pragma unroll 16
    for (unsigned c = 0; c < 64; ++c) {
        const unsigned j = (c << 6) | (unsigned)lane;   // strided: conflict-free
        const float d = cand_d2(pts4, j, ax, ay, az, sqi);
        const bool b1 = d < da, b2 = d < db, b3 = d < dc;
        const float n1 = fminf(da, d);
        const float n2 = __builtin_amdgcn_fmed3f(da, db, d);
        const float n3 = __builtin_amdgcn_fmed3f(db, dc, d);
        const unsigned m3 = b2 ? cb : (b3 ? c : cc);
        const unsigned m2 = b1 ? ca : (b2 ? c : cb);
        const unsigned m1 = b1 ? c : ca;
        da = n1; db = n2; dc = n3;
        ca = m1; cb = m2; cc = m3;
    }

    int cnt = 3;                 // valid entries in cache (64 cands >= 3)
    u64 used  = 0;               // per-lane consumed-candidate bits (by c)
    u64 wmask = 0;               // per-lane output-ownership bits
    u64 kk = ((u64)__float_as_uint(da) << 32) | (u64)((ca << 6) | (unsigned)lane);

    // ---- k extractions: wave-min of cached heads + winner-only cache pop ----
    for (int t = 0; t < k; ++t) {
        const u64 m = wave_min64(kk);
        const unsigned j = (unsigned)m;                   // winner index, uniform
        if (((j >> 2) & 63u) == (unsigned)lane)           // float4-owner lane
            wmask |= 1ull << (((j >> 8) << 2) | (j & 3u));
        if (m == kk) {                                    // lane bits -> unique winner
            used |= 1ull << ca;
            da = db; ca = cb;
            db = dc; cb = cc;
            dc = INF_F;
            if (--cnt == 0) {                             // rare: exec-skipped wave-wide
                float r1 = INF_F, r2 = INF_F, r3 = INF_F;
                unsigned e1 = 0, e2 = 0, e3 = 0;
                for (unsigned c = 0; c < 64; ++c) {
                    if (!((used >> c) & 1ull)) {
                        const float d = cand_d2(pts4, (c << 6) | (unsigned)lane,
                                                ax, ay, az, sqi);
                        const bool b1 = d < r1, b2 = d < r2, b3 = d < r3;
                        const float n1 = fminf(r1, d);
                        const float n2 = __builtin_amdgcn_fmed3f(r1, r2, d);
                        const float n3 = __builtin_amdgcn_fmed3f(r2, r3, d);
                        e3 = b2 ? e2 : (b3 ? c : e3);
                        e2 = b1 ? e1 : (b2 ? c : e2);
                        e1 = b1 ? c : e1;
                        r1 = n1; r2 = n2; r3 = n3;
                    }
                }
                da = r1; db = r2; dc = r3;
                ca = e1; cb = e2; cc = e3;
                const int navail = 64 - (int)__popcll(used);
                cnt = navail < 3 ? navail : 3;
            }
            kk = ((u64)__float_as_uint(da) << 32) | (u64)((ca << 6) | (unsigned)lane);
        }
    }

    // ---- emit row from register mask: coalesced float4 stream ----
    const float r = 1.0f / sqrtf((float)k);
    const float negrr = -__fmul_rn(r, r);      // -(dinv_i*dinv_j); deg == k exactly
    float4* o4 = (float4*)(out + (size_t)(b * Npts + i) * Npts);
#pragma unroll
    for (int q = 0; q < 16; ++q) {
        const int j0 = (q << 8) | (lane << 2); // element index of v.x
        float4 v;
        v.x = ((wmask >> (q * 4 + 0)) & 1ull) ? negrr : 0.0f;
        v.y = ((wmask >> (q * 4 + 1)) & 1ull) ? negrr : 0.0f;
        v.z = ((wmask >> (q * 4 + 2)) & 1ull) ? negrr : 0.0f;
        v.w = ((wmask >> (q * 4 + 3)) & 1ull) ? negrr : 0.0f;
        v.x = __fadd_rn(v.x, (j0 + 0 == i) ? 1.0f : 0.0f);
        v.y = __fadd_rn(v.y, (j0 + 1 == i) ? 1.0f : 0.0f);
        v.z = __fadd_rn(v.z, (j0 + 2 == i) ? 1.0f : 0.0f);
        v.w = __fadd_rn(v.w, (j0 + 3 == i) ? 1.0f : 0.0f);
        o4[(q << 6) | lane] = v;
    }
}

extern "C" void kernel_launch(void* const* d_in, const int* in_sizes, int n_in,
                              void* d_out, int out_size, void* d_ws, size_t ws_size,
                              hipStream_t stream) {
    const float* x    = (const float*)d_in[0];
    const int*   kptr = (const int*)d_in[1];
    float*       out  = (float*)d_out;
    const int B = in_sizes[0] / (Npts * 3);
    hipLaunchKernelGGL(gcn_lap_kernel, dim3(B * 512), dim3(BLK), 0, stream,
                       x, kptr, out);
}